// Round 5
// baseline (15.022 us; speedup 1.0000x reference)
//
#include <hip/hip_runtime.h>
#include <math.h>

// Local banded attention: B=2, L=2048, H=8, E=D=64, window w=7 (band=15).
// Block = 256 threads (4 waves) = 32 queries of one (b,h).
// Split-barrier pipeline: stage K -> barrier -> QK^T+softmax (V loads in
// flight) -> write V -> barrier -> PV.  K/V reg-staged into XOR-swizzled LDS
// (slot = rl*16 + (c4 ^ (rl&7))) so per-query private band reads (8 distinct
// rows per wave) are bank-even.  Wave: 8 queries x 8 lanes x 8 channels.
// Dot reduction = 3 DPP adds (VALU pipe, no DS traffic).

constexpr int L_DIM = 2048;
constexpr int H_DIM = 8;
constexpr int E_DIM = 64;
constexpr int W = 7;
constexpr int NK = 2 * W + 1;        // 15 band positions per query
constexpr int TQ = 32;               // queries per block
constexpr int HALO = 8;
constexpr int ROWS = TQ + 2 * HALO;  // 48 staged rows
constexpr int NCH = ROWS / 4;        // 12 chunks of 4 rows per matrix

template <int CTRL>
__device__ __forceinline__ float dpp_add(float s) {
  int t = __builtin_amdgcn_mov_dpp(__builtin_bit_cast(int, s), CTRL, 0xF, 0xF, true);
  return s + __builtin_bit_cast(float, t);
}

__global__ __launch_bounds__(256, 4) void local_attn_kernel(
    const float* __restrict__ q,
    const float* __restrict__ k,
    const float* __restrict__ v,
    float* __restrict__ out) {
  __shared__ float ks[ROWS * E_DIM];  // 12 KB
  __shared__ float vs[ROWS * E_DIM];  // 12 KB

  // XCD-aware swizzle (grid = 1024, divisible by 8): each XCD owns 2 (b,h).
  const int cpx = gridDim.x >> 3;
  const int bid = (blockIdx.x & 7) * cpx + (blockIdx.x >> 3);

  const int tile = bid & (L_DIM / TQ - 1);  // 64 tiles per (b,h)
  const int bh = bid >> 6;
  const int h = bh & (H_DIM - 1);
  const int b = bh >> 3;
  const int l0 = tile * TQ;

  const int tid = threadIdx.x;
  const int wv = tid >> 6;     // wave [0,4)
  const int lane = tid & 63;
  const int qsub = lane >> 3;  // query within wave [0,8)
  const int c = lane & 7;      // channel group [0,8) -> channels c*8..c*8+7

  const size_t bhb = (size_t)b * L_DIM * H_DIM + h;

  // ---- staging address pattern: chunk cc = 4 rows x 64 floats;
  // lane supplies row cc*4 + (lane>>4), 16B col group (lane&15).
  const int rsub = lane >> 4;
  const int c4 = lane & 15;

  int rl_s[3], slot_s[3];
  const float* ksrc[3];
#pragma unroll
  for (int t = 0; t < 3; ++t) {
    const int cc = wv + t * 4;     // this wave's chunks (0..11)
    const int rl = cc * 4 + rsub;  // LDS row 0..47
    int rg = l0 - HALO + rl;
    rg = rg < 0 ? 0 : (rg > L_DIM - 1 ? L_DIM - 1 : rg);
    rl_s[t] = rl;
    slot_s[t] = rl * 16 + (c4 ^ (rl & 7));
    ksrc[t] = k + ((bhb + (size_t)rg * H_DIM) << 6) + c4 * 4;
  }

  // Issue K loads first (needed first), then V, then Q.
  float4 stgK[3], stgV[3];
#pragma unroll
  for (int t = 0; t < 3; ++t) stgK[t] = *(const float4*)ksrc[t];
#pragma unroll
  for (int t = 0; t < 3; ++t)
    stgV[t] = *(const float4*)(v + (ksrc[t] - k));  // same row/col in V
  const int l0w = l0 + wv * 8;
  const int l = l0w + qsub;
  const float* qp = q + ((bhb + (size_t)l * H_DIM) << 6) + c * 8;
  float4 q0 = *(const float4*)qp;
  float4 q1 = *(const float4*)(qp + 4);

  // ---- write K (waits only on K loads), then barrier 1 ----
#pragma unroll
  for (int t = 0; t < 3; ++t) *(float4*)&ks[slot_s[t] * 4] = stgK[t];
  __syncthreads();

  const float scale = 0.125f;  // 1/sqrt(64)
  q0.x *= scale; q0.y *= scale; q0.z *= scale; q0.w *= scale;
  q1.x *= scale; q1.y *= scale; q1.z *= scale; q1.w *= scale;

  // ---- scores: each query group walks its own 15-key band ----
  // LDS row for band pos j: rl = wv*8 + 1 + qsub + j  (in [1,46])
  const int base_rl = wv * 8 + 1 + qsub;
  float sc[NK];
#pragma unroll
  for (int j = 0; j < NK; ++j) {
    const int rl = base_rl + j;
    const int s8 = rl & 7;
    const float4 k0 = *(const float4*)&ks[(rl * 16 + ((2 * c) ^ s8)) * 4];
    const float4 k1 = *(const float4*)&ks[(rl * 16 + ((2 * c + 1) ^ s8)) * 4];
    float s = q0.x * k0.x + q0.y * k0.y + q0.z * k0.z + q0.w * k0.w +
              q1.x * k1.x + q1.y * k1.y + q1.z * k1.z + q1.w * k1.w;
    s = dpp_add<0xB1>(s);   // xor 1 (quad_perm [1,0,3,2])
    s = dpp_add<0x4E>(s);   // xor 2 (quad_perm [2,3,0,1])
    s = dpp_add<0x141>(s);  // 8-lane half-row mirror
    const int kk = l0w + qsub - W + j;
    sc[j] = ((unsigned)kk < (unsigned)L_DIM) ? s : -INFINITY;
  }

  // ---- softmax over 15 band scores ----
  float mx = sc[0];
#pragma unroll
  for (int j = 1; j < NK; ++j) mx = fmaxf(mx, sc[j]);
  float den = 0.0f;
#pragma unroll
  for (int j = 0; j < NK; ++j) {
    sc[j] = __expf(sc[j] - mx);
    den += sc[j];
  }
  const float inv = __builtin_amdgcn_rcpf(den);

  // ---- write V (loads returned during score phase), barrier 2 ----
#pragma unroll
  for (int t = 0; t < 3; ++t) *(float4*)&vs[slot_s[t] * 4] = stgV[t];
  __syncthreads();

  // ---- PV: private-row walk over V ----
  float4 a0 = {0.f, 0.f, 0.f, 0.f};
  float4 a1 = {0.f, 0.f, 0.f, 0.f};
#pragma unroll
  for (int j = 0; j < NK; ++j) {
    const int rl = base_rl + j;
    const int s8 = rl & 7;
    const float4 v0 = *(const float4*)&vs[(rl * 16 + ((2 * c) ^ s8)) * 4];
    const float4 v1 = *(const float4*)&vs[(rl * 16 + ((2 * c + 1) ^ s8)) * 4];
    const float p = sc[j];
    a0.x += p * v0.x; a0.y += p * v0.y; a0.z += p * v0.z; a0.w += p * v0.w;
    a1.x += p * v1.x; a1.y += p * v1.y; a1.z += p * v1.z; a1.w += p * v1.w;
  }

  float* op = out + ((bhb + (size_t)l * H_DIM) << 6) + c * 8;
  a0.x *= inv; a0.y *= inv; a0.z *= inv; a0.w *= inv;
  a1.x *= inv; a1.y *= inv; a1.z *= inv; a1.w *= inv;
  *(float4*)op = a0;
  *(float4*)(op + 4) = a1;
}

extern "C" void kernel_launch(void* const* d_in, const int* in_sizes, int n_in,
                              void* d_out, int out_size, void* d_ws, size_t ws_size,
                              hipStream_t stream) {
  const float* q = (const float*)d_in[0];
  const float* k = (const float*)d_in[1];
  const float* v = (const float*)d_in[2];
  float* out = (float*)d_out;

  const int B = in_sizes[0] / (L_DIM * H_DIM * E_DIM);  // = 2
  const int blocks = B * H_DIM * (L_DIM / TQ);          // 1024

  local_attn_kernel<<<blocks, 256, 0, stream>>>(q, k, v, out);
}